// Round 3
// baseline (8929.107 us; speedup 1.0000x reference)
//
#include <hip/hip_runtime.h>

// ---------------- problem constants ----------------
constexpr int kB  = 64;
constexpr int kS  = 512;
constexpr int kF  = 64;
constexpr int kH  = 512;
constexpr int kL  = 4;
constexpr int kDH = 64;
constexpr int kC  = 32;              // chunk length
constexpr int kNC = kS / kC;         // 16 chunks
#define EPS 1e-5f

typedef __attribute__((ext_vector_type(8))) short short8;
typedef __attribute__((ext_vector_type(4))) float f32x4;

// ---------------- bf16 helpers ----------------
__device__ __forceinline__ ushort f2b(float f){
  unsigned u; __builtin_memcpy(&u, &f, 4);
  unsigned r = (u + 0x7fffu + ((u >> 16) & 1u)) >> 16;  // RNE
  return (ushort)r;
}
__device__ __forceinline__ float b2f(ushort u){
  unsigned v = ((unsigned)u) << 16; float f; __builtin_memcpy(&f, &v, 4); return f;
}
__device__ __forceinline__ void unpack2(unsigned u, float& a, float& b){
  unsigned lo = u << 16, hi = u & 0xffff0000u;
  __builtin_memcpy(&a, &lo, 4); __builtin_memcpy(&b, &hi, 4);
}

// ---------------- prep: fp32 -> bf16 cast with scale ----------------
__global__ void cast_scale(const float* __restrict__ src, ushort* __restrict__ dst,
                           int n, float s){
  int i = blockIdx.x*256 + threadIdx.x;
  if (i < n) dst[i] = f2b(src[i]*s);
}

// Afp[l][m][n] = (m==n ? 0.9 : 0) + float(bf16(0.1*Wh[l][n][m]))  -- row-major fp32
__global__ void prep_afp(const float* __restrict__ Wh, float* __restrict__ Afp){
  int i = blockIdx.x*256 + threadIdx.x;
  if (i >= kL*kH*kH) return;
  const int l = i >> 18, rem = i & 262143;
  const int m = rem >> 9, n = rem & 511;
  float v = b2f(f2b(0.1f * Wh[(size_t)l*kH*kH + (size_t)n*kH + m]));
  if (m == n) v += 0.9f;
  Afp[(size_t)l*kH*kH + (size_t)m*kH + n] = v;
}

// fp32 squaring GEMM, batched over 4 layers: Out[l] = In[l] @ In[l]
__global__ __launch_bounds__(512) void sqgemm(const float* __restrict__ In,
                                              float* __restrict__ Out){
  const int l = blockIdx.x >> 6;       // 4 layers
  const int rg = blockIdx.x & 63;      // row-group of 8
  const int j = threadIdx.x;
  const float* A = In + (size_t)l*kH*kH;
  float* C = Out + (size_t)l*kH*kH;
  __shared__ float ar[8][kH];
  #pragma unroll
  for (int r = 0; r < 8; ++r) ar[r][j] = A[(size_t)(rg*8 + r)*kH + j];
  __syncthreads();
  float acc[8] = {0,0,0,0,0,0,0,0};
  for (int k = 0; k < kH; ++k){
    const float bkj = A[(size_t)k*kH + j];
    #pragma unroll
    for (int r = 0; r < 8; ++r) acc[r] += ar[r][k] * bkj;
  }
  #pragma unroll
  for (int r = 0; r < 8; ++r) C[(size_t)(rg*8 + r)*kH + j] = acc[r];
}

// ---------------- MFMA GEMM: C[M,N](bf16) = A[M,K](bf16) @ W[N,K]^T + bias ----
__global__ __launch_bounds__(256) void gemm_bf16(
    const ushort* __restrict__ A, const ushort* __restrict__ W,
    ushort* __restrict__ C, int M, int N, int K,
    const float* __restrict__ pb1, const float* __restrict__ pb2, float bscale)
{
  const int wave = threadIdx.x >> 6, lane = threadIdx.x & 63;
  const int task = blockIdx.x*4 + wave;
  const int NT = N >> 6;
  const int mt = task / NT, ng = task % NT;
  const int r = lane & 15, quad = lane >> 4;

  const ushort* ap = A + (size_t)(mt*16 + r)*K + quad*8;
  const ushort* wp = W + (size_t)(ng*64 + r)*K + quad*8;
  f32x4 ac0 = {0,0,0,0}, ac1 = {0,0,0,0}, ac2 = {0,0,0,0}, ac3 = {0,0,0,0};
  for (int k0 = 0; k0 < K; k0 += 32){
    short8 av = *(const short8*)(ap + k0);
    short8 b0 = *(const short8*)(wp + k0);
    short8 b1 = *(const short8*)(wp + (size_t)16*K + k0);
    short8 b2 = *(const short8*)(wp + (size_t)32*K + k0);
    short8 b3 = *(const short8*)(wp + (size_t)48*K + k0);
    ac0 = __builtin_amdgcn_mfma_f32_16x16x32_bf16(av, b0, ac0, 0, 0, 0);
    ac1 = __builtin_amdgcn_mfma_f32_16x16x32_bf16(av, b1, ac1, 0, 0, 0);
    ac2 = __builtin_amdgcn_mfma_f32_16x16x32_bf16(av, b2, ac2, 0, 0, 0);
    ac3 = __builtin_amdgcn_mfma_f32_16x16x32_bf16(av, b3, ac3, 0, 0, 0);
  }
  const f32x4 accs[4] = {ac0, ac1, ac2, ac3};
  #pragma unroll
  for (int j = 0; j < 4; ++j){
    const int nn = ng*64 + j*16 + r;
    float bias = 0.f;
    if (pb1) bias += pb1[nn];
    if (pb2) bias += pb2[nn];
    bias *= bscale;
    #pragma unroll
    for (int i = 0; i < 4; ++i){
      const int mm = mt*16 + quad*4 + i;
      C[(size_t)mm*N + nn] = f2b(accs[j][i] + bias);
    }
  }
}

// ================= chunked scan, MFMA version (swapped operands) =================
// grid = 64 blocks = 16 chunks x 4 batch-groups of 16 batches; 8 waves/block.
// Per step: nh[16,512] = 0.9*h + U_t + (h_hi + h_lo)@G^T   (hi/lo bf16 split of h)
// MFMA roles: A = G rows (output cols), B = h (batch cols).
//   D col = lane&15 = batch, D row = quad*4+i = 4 CONSECUTIVE output cols
// -> all per-step global/LDS traffic vectorizes (8B packs).
// LDS tiles XOR-swizzled (byte ^= (row&7)<<4) for conflict-free ds_read_b128.
// FULL=false: zero-init, write chunk-end state to Z.
// FULL=true : init from S, write every step to nh (bf16).
template<bool FULL>
__global__ __launch_bounds__(512) void scan_mfma(
    const ushort* __restrict__ U,     // (B,S,H) bf16
    const ushort* __restrict__ G,     // (H,H) bf16 row-major [n][m] = bf16(0.1*Wh)
    const float* __restrict__ S,      // (B,NC,H) chunk-entry states (FULL only)
    float* __restrict__ Z,            // (B,NC,H) chunk-end states (!FULL only)
    ushort* __restrict__ nh)          // (B,S,H) bf16 (FULL only)
{
  const int c  = blockIdx.x & (kNC - 1);
  const int b0 = (blockIdx.x >> 4) * 16;
  const int wave = threadIdx.x >> 6, lane = threadIdx.x & 63;
  const int r = lane & 15, quad = lane >> 4;
  const int wbase = wave * 64;        // this wave's 64 output columns
  const int colq = quad * 4;          // column sub-offset within a 16-tile

  __shared__ __align__(16) ushort hiL[16*kH];
  __shared__ __align__(16) ushort loL[16*kH];
  char* hiB = (char*)hiL;
  char* loB = (char*)loL;

  // swizzled byte offset into a [16][512] bf16 tile
  #define SWZ(row, bytecol) ((row)*1024 + ((bytecol) ^ (((row)&7) << 4)))

  // G row pointers: tile t -> row wbase + t*16 + r, k-slice quad*8
  const ushort* gp0 = G + (size_t)(wbase +  0 + r)*kH + quad*8;
  const ushort* gp1 = G + (size_t)(wbase + 16 + r)*kH + quad*8;
  const ushort* gp2 = G + (size_t)(wbase + 32 + r)*kH + quad*8;
  const ushort* gp3 = G + (size_t)(wbase + 48 + r)*kH + quad*8;

  // this thread: batch = b0 + r; output cols wbase + t*16 + colq + i (i=0..3)
  float st[4][4];
  #pragma unroll
  for (int t = 0; t < 4; ++t){
    if (FULL){
      const float4 s4 = *(const float4*)&S[((size_t)(b0 + r)*kNC + c)*kH
                                           + wbase + t*16 + colq];
      st[t][0] = s4.x; st[t][1] = s4.y; st[t][2] = s4.z; st[t][3] = s4.w;
    } else {
      st[t][0] = st[t][1] = st[t][2] = st[t][3] = 0.f;
    }
  }

  // initial fragments (packed hi/lo, vector LDS writes)
  #pragma unroll
  for (int t = 0; t < 4; ++t){
    ushort h[4], l[4];
    #pragma unroll
    for (int i = 0; i < 4; ++i){
      h[i] = f2b(st[t][i]);
      l[i] = f2b(st[t][i] - b2f(h[i]));
    }
    uint2 hw, lw;
    hw.x = (unsigned)h[0] | ((unsigned)h[1] << 16);
    hw.y = (unsigned)h[2] | ((unsigned)h[3] << 16);
    lw.x = (unsigned)l[0] | ((unsigned)l[1] << 16);
    lw.y = (unsigned)l[2] | ((unsigned)l[3] << 16);
    const int bc = (wbase + t*16 + colq) * 2;
    *(uint2*)(hiB + SWZ(r, bc)) = hw;
    *(uint2*)(loB + SWZ(r, bc)) = lw;
  }
  __syncthreads();

  const size_t ubase = (size_t)(b0 + r)*kS*kH;

  for (int jj = 0; jj < kC; ++jj){
    const int tt = c*kC + jj;

    // prefetch this step's U (latency hides under the MFMA loop)
    uint2 uv[4];
    #pragma unroll
    for (int t = 0; t < 4; ++t)
      uv[t] = *(const uint2*)&U[ubase + (size_t)tt*kH + wbase + t*16 + colq];

    f32x4 ah0 = {0,0,0,0}, ah1 = {0,0,0,0}, ah2 = {0,0,0,0}, ah3 = {0,0,0,0};
    f32x4 al0 = {0,0,0,0}, al1 = {0,0,0,0}, al2 = {0,0,0,0}, al3 = {0,0,0,0};
    #pragma unroll 2
    for (int k0 = 0; k0 < kH; k0 += 32){
      const int rb = k0*2 + quad*16;   // 16B-aligned, swizzle-safe
      const short8 bh = *(const short8*)(hiB + SWZ(r, rb));
      const short8 bl = *(const short8*)(loB + SWZ(r, rb));
      const short8 g0 = *(const short8*)(gp0 + k0);
      const short8 g1 = *(const short8*)(gp1 + k0);
      const short8 g2 = *(const short8*)(gp2 + k0);
      const short8 g3 = *(const short8*)(gp3 + k0);
      ah0 = __builtin_amdgcn_mfma_f32_16x16x32_bf16(g0, bh, ah0, 0, 0, 0);
      ah1 = __builtin_amdgcn_mfma_f32_16x16x32_bf16(g1, bh, ah1, 0, 0, 0);
      ah2 = __builtin_amdgcn_mfma_f32_16x16x32_bf16(g2, bh, ah2, 0, 0, 0);
      ah3 = __builtin_amdgcn_mfma_f32_16x16x32_bf16(g3, bh, ah3, 0, 0, 0);
      al0 = __builtin_amdgcn_mfma_f32_16x16x32_bf16(g0, bl, al0, 0, 0, 0);
      al1 = __builtin_amdgcn_mfma_f32_16x16x32_bf16(g1, bl, al1, 0, 0, 0);
      al2 = __builtin_amdgcn_mfma_f32_16x16x32_bf16(g2, bl, al2, 0, 0, 0);
      al3 = __builtin_amdgcn_mfma_f32_16x16x32_bf16(g3, bl, al3, 0, 0, 0);
    }
    const f32x4 acs[4] = {ah0 + al0, ah1 + al1, ah2 + al2, ah3 + al3};
    __syncthreads();   // all fragment reads for this step are done

    #pragma unroll
    for (int t = 0; t < 4; ++t){
      float u0, u1, u2, u3;
      unpack2(uv[t].x, u0, u1); unpack2(uv[t].y, u2, u3);
      const float n0 = 0.9f*st[t][0] + u0 + acs[t][0];
      const float n1 = 0.9f*st[t][1] + u1 + acs[t][1];
      const float n2 = 0.9f*st[t][2] + u2 + acs[t][2];
      const float n3 = 0.9f*st[t][3] + u3 + acs[t][3];
      st[t][0] = n0; st[t][1] = n1; st[t][2] = n2; st[t][3] = n3;
      const ushort h0 = f2b(n0), h1 = f2b(n1), h2 = f2b(n2), h3 = f2b(n3);
      const ushort l0 = f2b(n0 - b2f(h0)), l1 = f2b(n1 - b2f(h1));
      const ushort l2 = f2b(n2 - b2f(h2)), l3 = f2b(n3 - b2f(h3));
      uint2 hw, lw;
      hw.x = (unsigned)h0 | ((unsigned)h1 << 16);
      hw.y = (unsigned)h2 | ((unsigned)h3 << 16);
      lw.x = (unsigned)l0 | ((unsigned)l1 << 16);
      lw.y = (unsigned)l2 | ((unsigned)l3 << 16);
      const int bc = (wbase + t*16 + colq) * 2;
      *(uint2*)(hiB + SWZ(r, bc)) = hw;
      *(uint2*)(loB + SWZ(r, bc)) = lw;
      if (FULL)
        *(uint2*)&nh[ubase + (size_t)tt*kH + wbase + t*16 + colq] = hw;
    }
    __syncthreads();   // new fragments visible
  }

  if (!FULL){
    #pragma unroll
    for (int t = 0; t < 4; ++t){
      float4 z4; z4.x = st[t][0]; z4.y = st[t][1]; z4.z = st[t][2]; z4.w = st[t][3];
      *(float4*)&Z[((size_t)(b0 + r)*kNC + c)*kH + wbase + t*16 + colq] = z4;
    }
  }
  #undef SWZ
}

// boundary recursion: S[b][c] = state entering chunk c; s' = s@A32 + Z[b][c]
__global__ __launch_bounds__(512) void scan_boundary(
    const float* __restrict__ A32, const float* __restrict__ Z,
    float* __restrict__ S)
{
  const int b = blockIdx.x, n = threadIdx.x;
  __shared__ float s[kH];
  s[n] = 0.f;
  __syncthreads();
  for (int c = 0; c < kNC; ++c){
    S[((size_t)b*kNC + c)*kH + n] = s[n];
    float acc = 0.f;
    for (int m = 0; m < kH; ++m) acc += s[m] * A32[(size_t)m*kH + n];
    const float nv = acc + Z[((size_t)b*kNC + c)*kH + n];
    __syncthreads();
    s[n] = nv;
    __syncthreads();
  }
}

// ---------------- LayerNorm rows (in place on bf16) ----------------
__global__ __launch_bounds__(512) void ln_rows(
    ushort* __restrict__ act, const float* __restrict__ g, const float* __restrict__ bta)
{
  const size_t row = blockIdx.x;
  const int n = threadIdx.x, wid = n >> 6, lane = n & 63;
  __shared__ float red[16];
  const float y = b2f(act[row*kH + n]);
  float s1 = y, s2 = y*y;
  #pragma unroll
  for (int off = 32; off; off >>= 1){
    s1 += __shfl_down(s1, off); s2 += __shfl_down(s2, off);
  }
  if (lane == 0){ red[wid] = s1; red[8 + wid] = s2; }
  __syncthreads();
  float m = 0.f, q = 0.f;
  #pragma unroll
  for (int i = 0; i < 8; ++i){ m += red[i]; q += red[8+i]; }
  m *= (1.f/kH); q *= (1.f/kH);
  const float var = q - m*m;
  const float hv = (y - m) * rsqrtf(var + EPS) * g[n] + bta[n];
  act[row*kH + n] = f2b(hv);
}

// ---------------- seqmean (fp32) from bf16 act ----------------
__global__ __launch_bounds__(512) void seqmean_k(
    const ushort* __restrict__ act, float* __restrict__ seqmean)
{
  const int b = blockIdx.x, n = threadIdx.x;
  float acc = 0.f;
  for (int t = 0; t < kS; ++t) acc += b2f(act[((size_t)b*kS + t)*kH + n]);
  seqmean[(size_t)b*kH + n] = acc * (1.f/kS);
}

// ---------------- flash attention on precomputed qkv (bf16) ----------------
__global__ __launch_bounds__(512) void attn_chunk(
    const ushort* __restrict__ qkv,   // (16*S, 3H) bf16
    float* __restrict__ aomean, int b0)
{
  const int bb = blockIdx.x >> 3, h = blockIdx.x & 7;
  const int tid = threadIdx.x, lane = tid & 63;
  __shared__ ushort kt[128][72];
  __shared__ ushort vt[128][72];
  __shared__ float aom[kDH];
  if (tid < kDH) aom[tid] = 0.f;

  float q[kDH], o[kDH];
  {
    const uint4* qp = (const uint4*)(qkv + ((size_t)bb*kS + tid)*(3*kH) + h*kDH);
    #pragma unroll
    for (int i = 0; i < 8; ++i){
      uint4 u = qp[i]; float f0,f1,f2,f3,f4,f5,f6,f7;
      unpack2(u.x,f0,f1); unpack2(u.y,f2,f3); unpack2(u.z,f4,f5); unpack2(u.w,f6,f7);
      q[i*8+0]=f0*0.125f; q[i*8+1]=f1*0.125f; q[i*8+2]=f2*0.125f; q[i*8+3]=f3*0.125f;
      q[i*8+4]=f4*0.125f; q[i*8+5]=f5*0.125f; q[i*8+6]=f6*0.125f; q[i*8+7]=f7*0.125f;
    }
  }
  #pragma unroll
  for (int d = 0; d < kDH; ++d) o[d] = 0.f;
  float mmax = -1e30f, lsum = 0.f;

  const int p  = tid & 127;
  const int dg = (tid >> 7) * 16;

  for (int t0 = 0; t0 < kS; t0 += 128){
    __syncthreads();
    const ushort* krow = qkv + ((size_t)bb*kS + t0 + p)*(3*kH) + kH   + h*kDH + dg;
    const ushort* vrow = qkv + ((size_t)bb*kS + t0 + p)*(3*kH) + 2*kH + h*kDH + dg;
    *(uint4*)&kt[p][dg]     = *(const uint4*)krow;
    *(uint4*)&kt[p][dg + 8] = *(const uint4*)(krow + 8);
    *(uint4*)&vt[p][dg]     = *(const uint4*)vrow;
    *(uint4*)&vt[p][dg + 8] = *(const uint4*)(vrow + 8);
    __syncthreads();

    for (int j = 0; j < 128; ++j){
      float s = 0.f;
      const uint4* kp = (const uint4*)&kt[j][0];
      #pragma unroll
      for (int i = 0; i < 8; ++i){
        uint4 u = kp[i]; float f0,f1,f2,f3,f4,f5,f6,f7;
        unpack2(u.x,f0,f1); unpack2(u.y,f2,f3); unpack2(u.z,f4,f5); unpack2(u.w,f6,f7);
        s += q[i*8+0]*f0 + q[i*8+1]*f1 + q[i*8+2]*f2 + q[i*8+3]*f3
           + q[i*8+4]*f4 + q[i*8+5]*f5 + q[i*8+6]*f6 + q[i*8+7]*f7;
      }
      if (s > mmax){
        const float corr = __expf(mmax - s);
        lsum *= corr;
        #pragma unroll
        for (int d = 0; d < kDH; ++d) o[d] *= corr;
        mmax = s;
      }
      const float pw = __expf(s - mmax);
      lsum += pw;
      const uint4* vp = (const uint4*)&vt[j][0];
      #pragma unroll
      for (int i = 0; i < 8; ++i){
        uint4 u = vp[i]; float f0,f1,f2,f3,f4,f5,f6,f7;
        unpack2(u.x,f0,f1); unpack2(u.y,f2,f3); unpack2(u.z,f4,f5); unpack2(u.w,f6,f7);
        o[i*8+0] += pw*f0; o[i*8+1] += pw*f1; o[i*8+2] += pw*f2; o[i*8+3] += pw*f3;
        o[i*8+4] += pw*f4; o[i*8+5] += pw*f5; o[i*8+6] += pw*f6; o[i*8+7] += pw*f7;
      }
    }
  }
  const float invl = 1.f / lsum;
  #pragma unroll
  for (int d = 0; d < kDH; ++d){
    float v = o[d] * invl;
    #pragma unroll
    for (int off = 32; off; off >>= 1) v += __shfl_down(v, off);
    if (lane == 0) atomicAdd(&aom[d], v);
  }
  __syncthreads();
  if (tid < kDH)
    aomean[(size_t)(b0 + bb)*kH + h*kDH + tid] = aom[tid] * (1.f/kS);
}

// ---- pooled = seqmean + aomean@out_w^T + out_b (fp32) ----
__global__ __launch_bounds__(512) void pooled_kernel(
    const float* __restrict__ seqmean, const float* __restrict__ aomean,
    const float* __restrict__ outw, const float* __restrict__ outb,
    float* __restrict__ pooled)
{
  const int b = blockIdx.x, n = threadIdx.x;
  __shared__ float a[kH];
  a[n] = aomean[(size_t)b*kH + n];
  __syncthreads();
  const float* w = outw + (size_t)n*kH;
  float acc = outb[n];
  for (int m = 0; m < kH; ++m) acc += w[m] * a[m];
  pooled[(size_t)b*kH + n] = seqmean[(size_t)b*kH + n] + acc;
}

// ---------------- heads (fp32, validated) ----------------
__global__ __launch_bounds__(256) void heads_kernel(
    const float* __restrict__ pooled,
    const float* Wd1, const float* bd1, const float* Wd2, const float* bd2,
    const float* Wd3, const float* bd3,
    const float* Wq1, const float* bq1, const float* Wq2, const float* bq2,
    const float* Wq3, const float* bq3,
    const float* Wc1, const float* bc1, const float* Wc2, const float* bc2,
    float* __restrict__ out)
{
  const int b = blockIdx.x, tid = threadIdx.x;
  __shared__ float p[kH];
  __shared__ float a1d[256], a1q[256], a1c[256];
  __shared__ float a2d[128], a2q[128];
  p[tid]       = pooled[(size_t)b*kH + tid];
  p[tid + 256] = pooled[(size_t)b*kH + tid + 256];
  __syncthreads();
  {
    const float *w1 = Wd1 + (size_t)tid*kH, *w2 = Wq1 + (size_t)tid*kH,
                *w3 = Wc1 + (size_t)tid*kH;
    float v1 = bd1[tid], v2 = bq1[tid], v3 = bc1[tid];
    for (int m = 0; m < kH; ++m){
      v1 += w1[m]*p[m]; v2 += w2[m]*p[m]; v3 += w3[m]*p[m];
    }
    a1d[tid] = fmaxf(v1, 0.f); a1q[tid] = fmaxf(v2, 0.f); a1c[tid] = fmaxf(v3, 0.f);
  }
  __syncthreads();
  if (tid < 128){
    const float *w1 = Wd2 + (size_t)tid*256, *w2 = Wq2 + (size_t)tid*256;
    float v1 = bd2[tid], v2 = bq2[tid];
    for (int m = 0; m < 256; ++m){ v1 += w1[m]*a1d[m]; v2 += w2[m]*a1q[m]; }
    a2d[tid] = fmaxf(v1, 0.f); a2q[tid] = fmaxf(v2, 0.f);
  }
  __syncthreads();
  if (tid == 0){
    float d0 = bd3[0], d1 = bd3[1], pr = bq3[0], c = bc2[0];
    for (int m = 0; m < 128; ++m){
      d0 += Wd3[m]*a2d[m]; d1 += Wd3[128+m]*a2d[m]; pr += Wq3[m]*a2q[m];
    }
    for (int m = 0; m < 256; ++m) c += Wc2[m]*a1c[m];
    c = 1.f / (1.f + __expf(-c));
    out[2*b + 0]  = d0;
    out[2*b + 1]  = d1;
    out[2*kB + b] = pr;
    out[3*kB + b] = c;
  }
}

// ---------------- launch ----------------
extern "C" void kernel_launch(void* const* d_in, const int* in_sizes, int n_in,
                              void* d_out, int out_size, void* d_ws, size_t ws_size,
                              hipStream_t stream) {
  const float* x    = (const float*)d_in[0];
  const float* Win0 = (const float*)d_in[1];
  const float* bin0 = (const float*)d_in[2];
  const float* Wi   = (const float*)d_in[3];
  const float* bi   = (const float*)d_in[4];
  const float* Wh   = (const float*)d_in[5];
  const float* bh   = (const float*)d_in[6];
  const float* Wo   = (const float*)d_in[7];
  const float* bo   = (const float*)d_in[8];
  const float* lng  = (const float*)d_in[9];
  const float* lnb  = (const float*)d_in[10];
  const float* ipw  = (const float*)d_in[11];
  const float* ipb  = (const float*)d_in[12];
  const float* outw = (const float*)d_in[13];
  const float* outb = (const float*)d_in[14];

  char* wsb = (char*)d_ws;
  const size_t MB = 1u << 20;
  ushort* act   = (ushort*)(wsb);               // 32 MiB
  ushort* U     = (ushort*)(wsb + 32*MB);       // 32 MiB (reused as qkv)
  ushort* nh    = (ushort*)(wsb + 64*MB);       // 32 MiB
  ushort* wh_bf = (ushort*)(wsb + 96*MB);       // 2 MiB (0.1-scaled Wh, row-major [n][m])
  ushort* wi_bf = (ushort*)(wsb + 98*MB);       // 2 MiB (0.1-scaled)
  ushort* wo_bf = (ushort*)(wsb + 100*MB);      // 2 MiB
  float*  Afp   = (float*)(wsb + 102*MB);       // 4 MiB (fp32 A powers, ping)
  float*  Afp2  = (float*)(wsb + 106*MB);       // 4 MiB (pong; holds A^32)
  float*  Z     = (float*)(wsb + 110*MB);       // 2 MiB (chunk-end zero-init states)
  float*  S     = (float*)(wsb + 112*MB);       // 2 MiB (chunk-entry true states)
  ushort* w0_bf = (ushort*)(wsb + 114*MB);      // 64 KiB
  ushort* ip_bf = (ushort*)(wsb + 114*MB + 65536);            // 1.5 MiB
  ushort* x_bf  = (ushort*)(wsb + 114*MB + 65536 + 1572864);  // 4 MiB
  char*   tail  = wsb + 114*MB + 65536 + 1572864 + 4194304;
  float* seqmean = (float*)tail;
  float* aomean  = seqmean + (size_t)kB*kH;
  float* pooled  = aomean  + (size_t)kB*kH;
  ushort* qkv    = U;   // overlay: U dead after scan phase

  // ---- prep casts ----
  cast_scale<<<(kB*kS*kF + 255)/256, 256, 0, stream>>>(x, x_bf, kB*kS*kF, 1.f);
  cast_scale<<<(kH*kF + 255)/256, 256, 0, stream>>>(Win0, w0_bf, kH*kF, 1.f);
  cast_scale<<<(kL*kH*kH + 255)/256, 256, 0, stream>>>(Wi, wi_bf, kL*kH*kH, 0.1f);
  cast_scale<<<(kL*kH*kH + 255)/256, 256, 0, stream>>>(Wo, wo_bf, kL*kH*kH, 1.f);
  cast_scale<<<(kL*kH*kH + 255)/256, 256, 0, stream>>>(Wh, wh_bf, kL*kH*kH, 0.1f);
  cast_scale<<<(3*kH*kH + 255)/256, 256, 0, stream>>>(ipw, ip_bf, 3*kH*kH, 1.f);
  prep_afp<<<(kL*kH*kH + 255)/256, 256, 0, stream>>>(Wh, Afp);
  // A^32 for all 4 layers via 5 fp32 squarings (ends in Afp2)
  sqgemm<<<kL*64, 512, 0, stream>>>(Afp,  Afp2);   // A^2
  sqgemm<<<kL*64, 512, 0, stream>>>(Afp2, Afp);    // A^4
  sqgemm<<<kL*64, 512, 0, stream>>>(Afp,  Afp2);   // A^8
  sqgemm<<<kL*64, 512, 0, stream>>>(Afp2, Afp);    // A^16
  sqgemm<<<kL*64, 512, 0, stream>>>(Afp,  Afp2);   // A^32

  constexpr int M = kB*kS;   // 32768
  gemm_bf16<<<(M/16)*(kH/64)/4, 256, 0, stream>>>(x_bf, w0_bf, act, M, kH, kF,
                                                  bin0, nullptr, 1.f);
  for (int l = 0; l < kL; ++l){
    gemm_bf16<<<(M/16)*(kH/64)/4, 256, 0, stream>>>(
        act, wi_bf + (size_t)l*kH*kH, U, M, kH, kH,
        bi + (size_t)l*kH, bh + (size_t)l*kH, 0.1f);
    scan_mfma<false><<<64, 512, 0, stream>>>(U, wh_bf + (size_t)l*kH*kH,
                                             nullptr, Z, nullptr);
    scan_boundary<<<kB, kH, 0, stream>>>(Afp2 + (size_t)l*kH*kH, Z, S);
    scan_mfma<true><<<64, 512, 0, stream>>>(U, wh_bf + (size_t)l*kH*kH,
                                            S, nullptr, nh);
    gemm_bf16<<<(M/16)*(kH/64)/4, 256, 0, stream>>>(
        nh, wo_bf + (size_t)l*kH*kH, act, M, kH, kH,
        bo + (size_t)l*kH, nullptr, 1.f);
    ln_rows<<<M, kH, 0, stream>>>(act, lng + (size_t)l*kH, lnb + (size_t)l*kH);
  }

  seqmean_k<<<kB, kH, 0, stream>>>(act, seqmean);

  for (int c = 0; c < 4; ++c){
    const int Mc = 16*kS;   // 8192
    gemm_bf16<<<(Mc/16)*(3*kH/64)/4, 256, 0, stream>>>(
        act + (size_t)c*Mc*kH, ip_bf, qkv, Mc, 3*kH, kH, ipb, nullptr, 1.f);
    attn_chunk<<<16*8, kH, 0, stream>>>(qkv, aomean, c*16);
  }

  pooled_kernel<<<kB, kH, 0, stream>>>(seqmean, aomean, outw, outb, pooled);

  heads_kernel<<<kB, 256, 0, stream>>>(pooled,
      (const float*)d_in[15], (const float*)d_in[16], (const float*)d_in[17],
      (const float*)d_in[18], (const float*)d_in[19], (const float*)d_in[20],
      (const float*)d_in[21], (const float*)d_in[22], (const float*)d_in[23],
      (const float*)d_in[24], (const float*)d_in[25], (const float*)d_in[26],
      (const float*)d_in[27], (const float*)d_in[28], (const float*)d_in[29],
      (const float*)d_in[30], (float*)d_out);
}

// Round 4
// 8017.591 us; speedup vs baseline: 1.1137x; 1.1137x over previous
//
#include <hip/hip_runtime.h>

// ---------------- problem constants ----------------
constexpr int kB  = 64;
constexpr int kS  = 512;
constexpr int kF  = 64;
constexpr int kH  = 512;
constexpr int kL  = 4;
constexpr int kDH = 64;
constexpr int kC  = 32;              // chunk length
constexpr int kNC = kS / kC;         // 16 chunks
#define EPS 1e-5f

typedef __attribute__((ext_vector_type(8))) short short8;
typedef __attribute__((ext_vector_type(4))) float f32x4;

// ---------------- bf16 helpers ----------------
__device__ __forceinline__ ushort f2b(float f){
  unsigned u; __builtin_memcpy(&u, &f, 4);
  unsigned r = (u + 0x7fffu + ((u >> 16) & 1u)) >> 16;  // RNE
  return (ushort)r;
}
__device__ __forceinline__ float b2f(ushort u){
  unsigned v = ((unsigned)u) << 16; float f; __builtin_memcpy(&f, &v, 4); return f;
}
__device__ __forceinline__ void unpack2(unsigned u, float& a, float& b){
  unsigned lo = u << 16, hi = u & 0xffff0000u;
  __builtin_memcpy(&a, &lo, 4); __builtin_memcpy(&b, &hi, 4);
}

// ---------------- prep: fp32 -> bf16 cast with scale ----------------
__global__ void cast_scale(const float* __restrict__ src, ushort* __restrict__ dst,
                           int n, float s){
  int i = blockIdx.x*256 + threadIdx.x;
  if (i < n) dst[i] = f2b(src[i]*s);
}

__global__ void zero_f32(float* __restrict__ p, int n){
  int i = blockIdx.x*256 + threadIdx.x;
  if (i < n) p[i] = 0.f;
}

// Afp[l][m][n] = (m==n ? 0.9 : 0) + float(bf16(0.1*Wh[l][n][m]))  -- row-major fp32
__global__ void prep_afp(const float* __restrict__ Wh, float* __restrict__ Afp){
  int i = blockIdx.x*256 + threadIdx.x;
  if (i >= kL*kH*kH) return;
  const int l = i >> 18, rem = i & 262143;
  const int m = rem >> 9, n = rem & 511;
  float v = b2f(f2b(0.1f * Wh[(size_t)l*kH*kH + (size_t)n*kH + m]));
  if (m == n) v += 0.9f;
  Afp[(size_t)l*kH*kH + (size_t)m*kH + n] = v;
}

// fp32 squaring GEMM, batched over 4 layers: Out[l] = In[l] @ In[l]
__global__ __launch_bounds__(512) void sqgemm(const float* __restrict__ In,
                                              float* __restrict__ Out){
  const int l = blockIdx.x >> 6;       // 4 layers
  const int rg = blockIdx.x & 63;      // row-group of 8
  const int j = threadIdx.x;
  const float* A = In + (size_t)l*kH*kH;
  float* C = Out + (size_t)l*kH*kH;
  __shared__ float ar[8][kH];
  #pragma unroll
  for (int r = 0; r < 8; ++r) ar[r][j] = A[(size_t)(rg*8 + r)*kH + j];
  __syncthreads();
  float acc[8] = {0,0,0,0,0,0,0,0};
  for (int k = 0; k < kH; ++k){
    const float bkj = A[(size_t)k*kH + j];
    #pragma unroll
    for (int r = 0; r < 8; ++r) acc[r] += ar[r][k] * bkj;
  }
  #pragma unroll
  for (int r = 0; r < 8; ++r) C[(size_t)(rg*8 + r)*kH + j] = acc[r];
}

// ---------------- MFMA GEMM: C[M,N](bf16) = A[M,K](bf16) @ W[N,K]^T + bias ----
__global__ __launch_bounds__(256) void gemm_bf16(
    const ushort* __restrict__ A, const ushort* __restrict__ W,
    ushort* __restrict__ C, int M, int N, int K,
    const float* __restrict__ pb1, const float* __restrict__ pb2, float bscale)
{
  const int wave = threadIdx.x >> 6, lane = threadIdx.x & 63;
  const int task = blockIdx.x*4 + wave;
  const int NT = N >> 6;
  const int mt = task / NT, ng = task % NT;
  const int r = lane & 15, quad = lane >> 4;

  const ushort* ap = A + (size_t)(mt*16 + r)*K + quad*8;
  const ushort* wp = W + (size_t)(ng*64 + r)*K + quad*8;
  f32x4 ac0 = {0,0,0,0}, ac1 = {0,0,0,0}, ac2 = {0,0,0,0}, ac3 = {0,0,0,0};
  for (int k0 = 0; k0 < K; k0 += 32){
    short8 av = *(const short8*)(ap + k0);
    short8 b0 = *(const short8*)(wp + k0);
    short8 b1 = *(const short8*)(wp + (size_t)16*K + k0);
    short8 b2 = *(const short8*)(wp + (size_t)32*K + k0);
    short8 b3 = *(const short8*)(wp + (size_t)48*K + k0);
    ac0 = __builtin_amdgcn_mfma_f32_16x16x32_bf16(av, b0, ac0, 0, 0, 0);
    ac1 = __builtin_amdgcn_mfma_f32_16x16x32_bf16(av, b1, ac1, 0, 0, 0);
    ac2 = __builtin_amdgcn_mfma_f32_16x16x32_bf16(av, b2, ac2, 0, 0, 0);
    ac3 = __builtin_amdgcn_mfma_f32_16x16x32_bf16(av, b3, ac3, 0, 0, 0);
  }
  const f32x4 accs[4] = {ac0, ac1, ac2, ac3};
  #pragma unroll
  for (int j = 0; j < 4; ++j){
    const int nn = ng*64 + j*16 + r;
    float bias = 0.f;
    if (pb1) bias += pb1[nn];
    if (pb2) bias += pb2[nn];
    bias *= bscale;
    #pragma unroll
    for (int i = 0; i < 4; ++i){
      const int mm = mt*16 + quad*4 + i;
      C[(size_t)mm*N + nn] = f2b(accs[j][i] + bias);
    }
  }
}

// ================= chunked scan, MFMA version (swapped operands) =================
// grid = 64 blocks = 16 chunks x 4 batch-groups of 16 batches; 8 waves/block.
// Per step: nh[16,512] = 0.9*h + U_t + (h_hi + h_lo)@G^T   (hi/lo bf16 split of h)
// MFMA roles: A = G rows (output cols), B = h (batch cols).
//   D col = lane&15 = batch, D row = quad*4+i = 4 CONSECUTIVE output cols
// -> all per-step global/LDS traffic vectorizes (8B packs).
// LDS tiles XOR-swizzled (byte ^= (row&7)<<4) for conflict-free ds_read_b128.
// FULL=false: zero-init, write chunk-end state to Z.
// FULL=true : init from S, write every step to nh (bf16).
template<bool FULL>
__global__ __launch_bounds__(512) void scan_mfma(
    const ushort* __restrict__ U,     // (B,S,H) bf16
    const ushort* __restrict__ G,     // (H,H) bf16 row-major [n][m] = bf16(0.1*Wh)
    const float* __restrict__ S,      // (B,NC,H) chunk-entry states (FULL only)
    float* __restrict__ Z,            // (B,NC,H) chunk-end states (!FULL only)
    ushort* __restrict__ nh)          // (B,S,H) bf16 (FULL only)
{
  const int c  = blockIdx.x & (kNC - 1);
  const int b0 = (blockIdx.x >> 4) * 16;
  const int wave = threadIdx.x >> 6, lane = threadIdx.x & 63;
  const int r = lane & 15, quad = lane >> 4;
  const int wbase = wave * 64;        // this wave's 64 output columns
  const int colq = quad * 4;          // column sub-offset within a 16-tile

  __shared__ __align__(16) ushort hiL[16*kH];
  __shared__ __align__(16) ushort loL[16*kH];
  char* hiB = (char*)hiL;
  char* loB = (char*)loL;

  // swizzled byte offset into a [16][512] bf16 tile
  #define SWZ(row, bytecol) ((row)*1024 + ((bytecol) ^ (((row)&7) << 4)))

  // G row pointers: tile t -> row wbase + t*16 + r, k-slice quad*8
  const ushort* gp0 = G + (size_t)(wbase +  0 + r)*kH + quad*8;
  const ushort* gp1 = G + (size_t)(wbase + 16 + r)*kH + quad*8;
  const ushort* gp2 = G + (size_t)(wbase + 32 + r)*kH + quad*8;
  const ushort* gp3 = G + (size_t)(wbase + 48 + r)*kH + quad*8;

  // this thread: batch = b0 + r; output cols wbase + t*16 + colq + i (i=0..3)
  float st[4][4];
  #pragma unroll
  for (int t = 0; t < 4; ++t){
    if (FULL){
      const float4 s4 = *(const float4*)&S[((size_t)(b0 + r)*kNC + c)*kH
                                           + wbase + t*16 + colq];
      st[t][0] = s4.x; st[t][1] = s4.y; st[t][2] = s4.z; st[t][3] = s4.w;
    } else {
      st[t][0] = st[t][1] = st[t][2] = st[t][3] = 0.f;
    }
  }

  // initial fragments (packed hi/lo, vector LDS writes)
  #pragma unroll
  for (int t = 0; t < 4; ++t){
    ushort h[4], l[4];
    #pragma unroll
    for (int i = 0; i < 4; ++i){
      h[i] = f2b(st[t][i]);
      l[i] = f2b(st[t][i] - b2f(h[i]));
    }
    uint2 hw, lw;
    hw.x = (unsigned)h[0] | ((unsigned)h[1] << 16);
    hw.y = (unsigned)h[2] | ((unsigned)h[3] << 16);
    lw.x = (unsigned)l[0] | ((unsigned)l[1] << 16);
    lw.y = (unsigned)l[2] | ((unsigned)l[3] << 16);
    const int bc = (wbase + t*16 + colq) * 2;
    *(uint2*)(hiB + SWZ(r, bc)) = hw;
    *(uint2*)(loB + SWZ(r, bc)) = lw;
  }
  __syncthreads();

  const size_t ubase = (size_t)(b0 + r)*kS*kH;

  for (int jj = 0; jj < kC; ++jj){
    const int tt = c*kC + jj;

    // prefetch this step's U (latency hides under the MFMA loop)
    uint2 uv[4];
    #pragma unroll
    for (int t = 0; t < 4; ++t)
      uv[t] = *(const uint2*)&U[ubase + (size_t)tt*kH + wbase + t*16 + colq];

    f32x4 ah0 = {0,0,0,0}, ah1 = {0,0,0,0}, ah2 = {0,0,0,0}, ah3 = {0,0,0,0};
    f32x4 al0 = {0,0,0,0}, al1 = {0,0,0,0}, al2 = {0,0,0,0}, al3 = {0,0,0,0};
    #pragma unroll 2
    for (int k0 = 0; k0 < kH; k0 += 32){
      const int rb = k0*2 + quad*16;   // 16B-aligned, swizzle-safe
      const short8 bh = *(const short8*)(hiB + SWZ(r, rb));
      const short8 bl = *(const short8*)(loB + SWZ(r, rb));
      const short8 g0 = *(const short8*)(gp0 + k0);
      const short8 g1 = *(const short8*)(gp1 + k0);
      const short8 g2 = *(const short8*)(gp2 + k0);
      const short8 g3 = *(const short8*)(gp3 + k0);
      ah0 = __builtin_amdgcn_mfma_f32_16x16x32_bf16(g0, bh, ah0, 0, 0, 0);
      ah1 = __builtin_amdgcn_mfma_f32_16x16x32_bf16(g1, bh, ah1, 0, 0, 0);
      ah2 = __builtin_amdgcn_mfma_f32_16x16x32_bf16(g2, bh, ah2, 0, 0, 0);
      ah3 = __builtin_amdgcn_mfma_f32_16x16x32_bf16(g3, bh, ah3, 0, 0, 0);
      al0 = __builtin_amdgcn_mfma_f32_16x16x32_bf16(g0, bl, al0, 0, 0, 0);
      al1 = __builtin_amdgcn_mfma_f32_16x16x32_bf16(g1, bl, al1, 0, 0, 0);
      al2 = __builtin_amdgcn_mfma_f32_16x16x32_bf16(g2, bl, al2, 0, 0, 0);
      al3 = __builtin_amdgcn_mfma_f32_16x16x32_bf16(g3, bl, al3, 0, 0, 0);
    }
    const f32x4 acs[4] = {ah0 + al0, ah1 + al1, ah2 + al2, ah3 + al3};
    __syncthreads();   // all fragment reads for this step are done

    #pragma unroll
    for (int t = 0; t < 4; ++t){
      float u0, u1, u2, u3;
      unpack2(uv[t].x, u0, u1); unpack2(uv[t].y, u2, u3);
      const float n0 = 0.9f*st[t][0] + u0 + acs[t][0];
      const float n1 = 0.9f*st[t][1] + u1 + acs[t][1];
      const float n2 = 0.9f*st[t][2] + u2 + acs[t][2];
      const float n3 = 0.9f*st[t][3] + u3 + acs[t][3];
      st[t][0] = n0; st[t][1] = n1; st[t][2] = n2; st[t][3] = n3;
      const ushort h0 = f2b(n0), h1 = f2b(n1), h2 = f2b(n2), h3 = f2b(n3);
      const ushort l0 = f2b(n0 - b2f(h0)), l1 = f2b(n1 - b2f(h1));
      const ushort l2 = f2b(n2 - b2f(h2)), l3 = f2b(n3 - b2f(h3));
      uint2 hw, lw;
      hw.x = (unsigned)h0 | ((unsigned)h1 << 16);
      hw.y = (unsigned)h2 | ((unsigned)h3 << 16);
      lw.x = (unsigned)l0 | ((unsigned)l1 << 16);
      lw.y = (unsigned)l2 | ((unsigned)l3 << 16);
      const int bc = (wbase + t*16 + colq) * 2;
      *(uint2*)(hiB + SWZ(r, bc)) = hw;
      *(uint2*)(loB + SWZ(r, bc)) = lw;
      if (FULL)
        *(uint2*)&nh[ubase + (size_t)tt*kH + wbase + t*16 + colq] = hw;
    }
    __syncthreads();   // new fragments visible
  }

  if (!FULL){
    #pragma unroll
    for (int t = 0; t < 4; ++t){
      float4 z4; z4.x = st[t][0]; z4.y = st[t][1]; z4.z = st[t][2]; z4.w = st[t][3];
      *(float4*)&Z[((size_t)(b0 + r)*kNC + c)*kH + wbase + t*16 + colq] = z4;
    }
  }
  #undef SWZ
}

// boundary recursion: S[b][c] = state entering chunk c; s' = s@A32 + Z[b][c]
__global__ __launch_bounds__(512) void scan_boundary(
    const float* __restrict__ A32, const float* __restrict__ Z,
    float* __restrict__ S)
{
  const int b = blockIdx.x, n = threadIdx.x;
  __shared__ float s[kH];
  s[n] = 0.f;
  __syncthreads();
  for (int c = 0; c < kNC; ++c){
    S[((size_t)b*kNC + c)*kH + n] = s[n];
    float acc = 0.f;
    for (int m = 0; m < kH; ++m) acc += s[m] * A32[(size_t)m*kH + n];
    const float nv = acc + Z[((size_t)b*kNC + c)*kH + n];
    __syncthreads();
    s[n] = nv;
    __syncthreads();
  }
}

// ---------------- LayerNorm rows (in place on bf16) ----------------
__global__ __launch_bounds__(512) void ln_rows(
    ushort* __restrict__ act, const float* __restrict__ g, const float* __restrict__ bta)
{
  const size_t row = blockIdx.x;
  const int n = threadIdx.x, wid = n >> 6, lane = n & 63;
  __shared__ float red[16];
  const float y = b2f(act[row*kH + n]);
  float s1 = y, s2 = y*y;
  #pragma unroll
  for (int off = 32; off; off >>= 1){
    s1 += __shfl_down(s1, off); s2 += __shfl_down(s2, off);
  }
  if (lane == 0){ red[wid] = s1; red[8 + wid] = s2; }
  __syncthreads();
  float m = 0.f, q = 0.f;
  #pragma unroll
  for (int i = 0; i < 8; ++i){ m += red[i]; q += red[8+i]; }
  m *= (1.f/kH); q *= (1.f/kH);
  const float var = q - m*m;
  const float hv = (y - m) * rsqrtf(var + EPS) * g[n] + bta[n];
  act[row*kH + n] = f2b(hv);
}

// ---------------- seqmean (fp32) from bf16 act ----------------
__global__ __launch_bounds__(512) void seqmean_k(
    const ushort* __restrict__ act, float* __restrict__ seqmean)
{
  const int b = blockIdx.x, n = threadIdx.x;
  float acc = 0.f;
  for (int t = 0; t < kS; ++t) acc += b2f(act[((size_t)b*kS + t)*kH + n]);
  seqmean[(size_t)b*kH + n] = acc * (1.f/kS);
}

// ---------------- flash attention on precomputed qkv (bf16) ----------------
// Split layout: grid = 16 batches x 8 heads x 2 query-halves = 256 blocks.
// Within a wave: lane = 2*qi + dh. Each lane owns one query (qi) and HALF the
// head dim (dh*32..dh*32+31). Dot = 32 FMA + shfl_xor(1) combine; o = 32 fp32.
// Partial query-mean accumulated via atomicAdd into pre-zeroed aomean.
__global__ __launch_bounds__(512) void attn_chunk(
    const ushort* __restrict__ qkv,   // (16*S, 3H) bf16
    float* __restrict__ aomean, int b0)
{
  const int bb = blockIdx.x >> 4;          // batch within chunk
  const int h  = (blockIdx.x >> 1) & 7;    // head
  const int qh = blockIdx.x & 1;           // query half
  const int tid = threadIdx.x, lane = tid & 63, wave = tid >> 6;
  const int dh = lane & 1;                 // dim half
  const int q  = qh*256 + wave*32 + (lane >> 1);

  __shared__ ushort kt[128][72];
  __shared__ ushort vt[128][72];
  __shared__ float aom[kDH];
  if (tid < kDH) aom[tid] = 0.f;

  float qv[32], o[32];
  {
    const uint4* qp = (const uint4*)(qkv + ((size_t)bb*kS + q)*(3*kH) + h*kDH + dh*32);
    #pragma unroll
    for (int i = 0; i < 4; ++i){
      uint4 u = qp[i]; float f0,f1,f2,f3,f4,f5,f6,f7;
      unpack2(u.x,f0,f1); unpack2(u.y,f2,f3); unpack2(u.z,f4,f5); unpack2(u.w,f6,f7);
      qv[i*8+0]=f0*0.125f; qv[i*8+1]=f1*0.125f; qv[i*8+2]=f2*0.125f; qv[i*8+3]=f3*0.125f;
      qv[i*8+4]=f4*0.125f; qv[i*8+5]=f5*0.125f; qv[i*8+6]=f6*0.125f; qv[i*8+7]=f7*0.125f;
    }
  }
  #pragma unroll
  for (int d = 0; d < 32; ++d) o[d] = 0.f;
  float mmax = -1e30f, lsum = 0.f;

  const int p  = tid & 127;
  const int dg = (tid >> 7) * 16;

  for (int t0 = 0; t0 < kS; t0 += 128){
    __syncthreads();
    const ushort* krow = qkv + ((size_t)bb*kS + t0 + p)*(3*kH) + kH   + h*kDH + dg;
    const ushort* vrow = qkv + ((size_t)bb*kS + t0 + p)*(3*kH) + 2*kH + h*kDH + dg;
    *(uint4*)&kt[p][dg]     = *(const uint4*)krow;
    *(uint4*)&kt[p][dg + 8] = *(const uint4*)(krow + 8);
    *(uint4*)&vt[p][dg]     = *(const uint4*)vrow;
    *(uint4*)&vt[p][dg + 8] = *(const uint4*)(vrow + 8);
    __syncthreads();

    for (int j = 0; j < 128; ++j){
      float sh = 0.f;
      const uint4* kp = (const uint4*)&kt[j][dh*32];
      #pragma unroll
      for (int i = 0; i < 4; ++i){
        uint4 u = kp[i]; float f0,f1,f2,f3,f4,f5,f6,f7;
        unpack2(u.x,f0,f1); unpack2(u.y,f2,f3); unpack2(u.z,f4,f5); unpack2(u.w,f6,f7);
        sh += qv[i*8+0]*f0 + qv[i*8+1]*f1 + qv[i*8+2]*f2 + qv[i*8+3]*f3
            + qv[i*8+4]*f4 + qv[i*8+5]*f5 + qv[i*8+6]*f6 + qv[i*8+7]*f7;
      }
      const float s = sh + __shfl_xor(sh, 1);   // combine the two dim-halves
      if (s > mmax){
        const float corr = __expf(mmax - s);
        lsum *= corr;
        #pragma unroll
        for (int d = 0; d < 32; ++d) o[d] *= corr;
        mmax = s;
      }
      const float pw = __expf(s - mmax);
      lsum += pw;
      const uint4* vp = (const uint4*)&vt[j][dh*32];
      #pragma unroll
      for (int i = 0; i < 4; ++i){
        uint4 u = vp[i]; float f0,f1,f2,f3,f4,f5,f6,f7;
        unpack2(u.x,f0,f1); unpack2(u.y,f2,f3); unpack2(u.z,f4,f5); unpack2(u.w,f6,f7);
        o[i*8+0] += pw*f0; o[i*8+1] += pw*f1; o[i*8+2] += pw*f2; o[i*8+3] += pw*f3;
        o[i*8+4] += pw*f4; o[i*8+5] += pw*f5; o[i*8+6] += pw*f6; o[i*8+7] += pw*f7;
      }
    }
  }
  // per-lane scale; reduce over the 32 same-parity lanes (queries in this wave)
  const float invl = (1.f / lsum) * (1.f/kS);
  #pragma unroll
  for (int d = 0; d < 32; ++d){
    float v = o[d] * invl;
    #pragma unroll
    for (int off = 2; off < 64; off <<= 1) v += __shfl_xor(v, off);
    if ((lane >> 1) == 0) atomicAdd(&aom[dh*32 + d], v);  // lanes 0 and 1
  }
  __syncthreads();
  if (tid < kDH)
    atomicAdd(&aomean[(size_t)(b0 + bb)*kH + h*kDH + tid], aom[tid]);
}

// ---- pooled = seqmean + aomean@out_w^T + out_b (fp32) ----
__global__ __launch_bounds__(512) void pooled_kernel(
    const float* __restrict__ seqmean, const float* __restrict__ aomean,
    const float* __restrict__ outw, const float* __restrict__ outb,
    float* __restrict__ pooled)
{
  const int b = blockIdx.x, n = threadIdx.x;
  __shared__ float a[kH];
  a[n] = aomean[(size_t)b*kH + n];
  __syncthreads();
  const float* w = outw + (size_t)n*kH;
  float acc = outb[n];
  for (int m = 0; m < kH; ++m) acc += w[m] * a[m];
  pooled[(size_t)b*kH + n] = seqmean[(size_t)b*kH + n] + acc;
}

// ---------------- heads (fp32, validated) ----------------
__global__ __launch_bounds__(256) void heads_kernel(
    const float* __restrict__ pooled,
    const float* Wd1, const float* bd1, const float* Wd2, const float* bd2,
    const float* Wd3, const float* bd3,
    const float* Wq1, const float* bq1, const float* Wq2, const float* bq2,
    const float* Wq3, const float* bq3,
    const float* Wc1, const float* bc1, const float* Wc2, const float* bc2,
    float* __restrict__ out)
{
  const int b = blockIdx.x, tid = threadIdx.x;
  __shared__ float p[kH];
  __shared__ float a1d[256], a1q[256], a1c[256];
  __shared__ float a2d[128], a2q[128];
  p[tid]       = pooled[(size_t)b*kH + tid];
  p[tid + 256] = pooled[(size_t)b*kH + tid + 256];
  __syncthreads();
  {
    const float *w1 = Wd1 + (size_t)tid*kH, *w2 = Wq1 + (size_t)tid*kH,
                *w3 = Wc1 + (size_t)tid*kH;
    float v1 = bd1[tid], v2 = bq1[tid], v3 = bc1[tid];
    for (int m = 0; m < kH; ++m){
      v1 += w1[m]*p[m]; v2 += w2[m]*p[m]; v3 += w3[m]*p[m];
    }
    a1d[tid] = fmaxf(v1, 0.f); a1q[tid] = fmaxf(v2, 0.f); a1c[tid] = fmaxf(v3, 0.f);
  }
  __syncthreads();
  if (tid < 128){
    const float *w1 = Wd2 + (size_t)tid*256, *w2 = Wq2 + (size_t)tid*256;
    float v1 = bd2[tid], v2 = bq2[tid];
    for (int m = 0; m < 256; ++m){ v1 += w1[m]*a1d[m]; v2 += w2[m]*a1q[m]; }
    a2d[tid] = fmaxf(v1, 0.f); a2q[tid] = fmaxf(v2, 0.f);
  }
  __syncthreads();
  if (tid == 0){
    float d0 = bd3[0], d1 = bd3[1], pr = bq3[0], c = bc2[0];
    for (int m = 0; m < 128; ++m){
      d0 += Wd3[m]*a2d[m]; d1 += Wd3[128+m]*a2d[m]; pr += Wq3[m]*a2q[m];
    }
    for (int m = 0; m < 256; ++m) c += Wc2[m]*a1c[m];
    c = 1.f / (1.f + __expf(-c));
    out[2*b + 0]  = d0;
    out[2*b + 1]  = d1;
    out[2*kB + b] = pr;
    out[3*kB + b] = c;
  }
}

// ---------------- launch ----------------
extern "C" void kernel_launch(void* const* d_in, const int* in_sizes, int n_in,
                              void* d_out, int out_size, void* d_ws, size_t ws_size,
                              hipStream_t stream) {
  const float* x    = (const float*)d_in[0];
  const float* Win0 = (const float*)d_in[1];
  const float* bin0 = (const float*)d_in[2];
  const float* Wi   = (const float*)d_in[3];
  const float* bi   = (const float*)d_in[4];
  const float* Wh   = (const float*)d_in[5];
  const float* bh   = (const float*)d_in[6];
  const float* Wo   = (const float*)d_in[7];
  const float* bo   = (const float*)d_in[8];
  const float* lng  = (const float*)d_in[9];
  const float* lnb  = (const float*)d_in[10];
  const float* ipw  = (const float*)d_in[11];
  const float* ipb  = (const float*)d_in[12];
  const float* outw = (const float*)d_in[13];
  const float* outb = (const float*)d_in[14];

  char* wsb = (char*)d_ws;
  const size_t MB = 1u << 20;
  ushort* act   = (ushort*)(wsb);               // 32 MiB
  ushort* U     = (ushort*)(wsb + 32*MB);       // 32 MiB (reused as qkv)
  ushort* nh    = (ushort*)(wsb + 64*MB);       // 32 MiB
  ushort* wh_bf = (ushort*)(wsb + 96*MB);       // 2 MiB (0.1-scaled Wh, row-major [n][m])
  ushort* wi_bf = (ushort*)(wsb + 98*MB);       // 2 MiB (0.1-scaled)
  ushort* wo_bf = (ushort*)(wsb + 100*MB);      // 2 MiB
  float*  Afp   = (float*)(wsb + 102*MB);       // 4 MiB (fp32 A powers, ping)
  float*  Afp2  = (float*)(wsb + 106*MB);       // 4 MiB (pong; holds A^32)
  float*  Z     = (float*)(wsb + 110*MB);       // 2 MiB (chunk-end zero-init states)
  float*  S     = (float*)(wsb + 112*MB);       // 2 MiB (chunk-entry true states)
  ushort* w0_bf = (ushort*)(wsb + 114*MB);      // 64 KiB
  ushort* ip_bf = (ushort*)(wsb + 114*MB + 65536);            // 1.5 MiB
  ushort* x_bf  = (ushort*)(wsb + 114*MB + 65536 + 1572864);  // 4 MiB
  char*   tail  = wsb + 114*MB + 65536 + 1572864 + 4194304;
  float* seqmean = (float*)tail;
  float* aomean  = seqmean + (size_t)kB*kH;
  float* pooled  = aomean  + (size_t)kB*kH;
  ushort* qkv    = U;   // overlay: U dead after scan phase

  // ---- prep casts ----
  cast_scale<<<(kB*kS*kF + 255)/256, 256, 0, stream>>>(x, x_bf, kB*kS*kF, 1.f);
  cast_scale<<<(kH*kF + 255)/256, 256, 0, stream>>>(Win0, w0_bf, kH*kF, 1.f);
  cast_scale<<<(kL*kH*kH + 255)/256, 256, 0, stream>>>(Wi, wi_bf, kL*kH*kH, 0.1f);
  cast_scale<<<(kL*kH*kH + 255)/256, 256, 0, stream>>>(Wo, wo_bf, kL*kH*kH, 1.f);
  cast_scale<<<(kL*kH*kH + 255)/256, 256, 0, stream>>>(Wh, wh_bf, kL*kH*kH, 0.1f);
  cast_scale<<<(3*kH*kH + 255)/256, 256, 0, stream>>>(ipw, ip_bf, 3*kH*kH, 1.f);
  prep_afp<<<(kL*kH*kH + 255)/256, 256, 0, stream>>>(Wh, Afp);
  // A^32 for all 4 layers via 5 fp32 squarings (ends in Afp2)
  sqgemm<<<kL*64, 512, 0, stream>>>(Afp,  Afp2);   // A^2
  sqgemm<<<kL*64, 512, 0, stream>>>(Afp2, Afp);    // A^4
  sqgemm<<<kL*64, 512, 0, stream>>>(Afp,  Afp2);   // A^8
  sqgemm<<<kL*64, 512, 0, stream>>>(Afp2, Afp);    // A^16
  sqgemm<<<kL*64, 512, 0, stream>>>(Afp,  Afp2);   // A^32

  constexpr int M = kB*kS;   // 32768
  gemm_bf16<<<(M/16)*(kH/64)/4, 256, 0, stream>>>(x_bf, w0_bf, act, M, kH, kF,
                                                  bin0, nullptr, 1.f);
  for (int l = 0; l < kL; ++l){
    gemm_bf16<<<(M/16)*(kH/64)/4, 256, 0, stream>>>(
        act, wi_bf + (size_t)l*kH*kH, U, M, kH, kH,
        bi + (size_t)l*kH, bh + (size_t)l*kH, 0.1f);
    scan_mfma<false><<<64, 512, 0, stream>>>(U, wh_bf + (size_t)l*kH*kH,
                                             nullptr, Z, nullptr);
    scan_boundary<<<kB, kH, 0, stream>>>(Afp2 + (size_t)l*kH*kH, Z, S);
    scan_mfma<true><<<64, 512, 0, stream>>>(U, wh_bf + (size_t)l*kH*kH,
                                            S, nullptr, nh);
    gemm_bf16<<<(M/16)*(kH/64)/4, 256, 0, stream>>>(
        nh, wo_bf + (size_t)l*kH*kH, act, M, kH, kH,
        bo + (size_t)l*kH, nullptr, 1.f);
    ln_rows<<<M, kH, 0, stream>>>(act, lng + (size_t)l*kH, lnb + (size_t)l*kH);
  }

  seqmean_k<<<kB, kH, 0, stream>>>(act, seqmean);

  zero_f32<<<(kB*kH + 255)/256, 256, 0, stream>>>(aomean, kB*kH);
  for (int c = 0; c < 4; ++c){
    const int Mc = 16*kS;   // 8192
    gemm_bf16<<<(Mc/16)*(3*kH/64)/4, 256, 0, stream>>>(
        act + (size_t)c*Mc*kH, ip_bf, qkv, Mc, 3*kH, kH, ipb, nullptr, 1.f);
    attn_chunk<<<16*8*2, 512, 0, stream>>>(qkv, aomean, c*16);
  }

  pooled_kernel<<<kB, kH, 0, stream>>>(seqmean, aomean, outw, outb, pooled);

  heads_kernel<<<kB, 256, 0, stream>>>(pooled,
      (const float*)d_in[15], (const float*)d_in[16], (const float*)d_in[17],
      (const float*)d_in[18], (const float*)d_in[19], (const float*)d_in[20],
      (const float*)d_in[21], (const float*)d_in[22], (const float*)d_in[23],
      (const float*)d_in[24], (const float*)d_in[25], (const float*)d_in[26],
      (const float*)d_in[27], (const float*)d_in[28], (const float*)d_in[29],
      (const float*)d_in[30], (float*)d_out);
}

// Round 5
// 6450.715 us; speedup vs baseline: 1.3842x; 1.2429x over previous
//
#include <hip/hip_runtime.h>

// ---------------- problem constants ----------------
constexpr int kB  = 64;
constexpr int kS  = 512;
constexpr int kF  = 64;
constexpr int kH  = 512;
constexpr int kL  = 4;
constexpr int kDH = 64;
constexpr int kC  = 16;              // chunk length (16 steps per scan dispatch)
constexpr int kNC = kS / kC;         // 32 chunks
#define EPS 1e-5f

typedef __attribute__((ext_vector_type(8))) short short8;
typedef __attribute__((ext_vector_type(4))) float f32x4;

// ---------------- bf16 helpers ----------------
__device__ __forceinline__ ushort f2b(float f){
  unsigned u; __builtin_memcpy(&u, &f, 4);
  unsigned r = (u + 0x7fffu + ((u >> 16) & 1u)) >> 16;  // RNE
  return (ushort)r;
}
__device__ __forceinline__ float b2f(ushort u){
  unsigned v = ((unsigned)u) << 16; float f; __builtin_memcpy(&f, &v, 4); return f;
}
__device__ __forceinline__ void unpack2(unsigned u, float& a, float& b){
  unsigned lo = u << 16, hi = u & 0xffff0000u;
  __builtin_memcpy(&a, &lo, 4); __builtin_memcpy(&b, &hi, 4);
}

// ---------------- prep: fp32 -> bf16 cast with scale ----------------
__global__ void cast_scale(const float* __restrict__ src, ushort* __restrict__ dst,
                           int n, float s){
  int i = blockIdx.x*256 + threadIdx.x;
  if (i < n) dst[i] = f2b(src[i]*s);
}

__global__ void zero_f32(float* __restrict__ p, int n){
  int i = blockIdx.x*256 + threadIdx.x;
  if (i < n) p[i] = 0.f;
}

// Afp[l][m][n] = (m==n ? 0.9 : 0) + float(bf16(0.1*Wh[l][n][m]))  -- row-major fp32
__global__ void prep_afp(const float* __restrict__ Wh, float* __restrict__ Afp){
  int i = blockIdx.x*256 + threadIdx.x;
  if (i >= kL*kH*kH) return;
  const int l = i >> 18, rem = i & 262143;
  const int m = rem >> 9, n = rem & 511;
  float v = b2f(f2b(0.1f * Wh[(size_t)l*kH*kH + (size_t)n*kH + m]));
  if (m == n) v += 0.9f;
  Afp[(size_t)l*kH*kH + (size_t)m*kH + n] = v;
}

// fp32 squaring GEMM, batched over 4 layers: Out[l] = In[l] @ In[l]
__global__ __launch_bounds__(512) void sqgemm(const float* __restrict__ In,
                                              float* __restrict__ Out){
  const int l = blockIdx.x >> 6;       // 4 layers
  const int rg = blockIdx.x & 63;      // row-group of 8
  const int j = threadIdx.x;
  const float* A = In + (size_t)l*kH*kH;
  float* C = Out + (size_t)l*kH*kH;
  __shared__ float ar[8][kH];
  #pragma unroll
  for (int r = 0; r < 8; ++r) ar[r][j] = A[(size_t)(rg*8 + r)*kH + j];
  __syncthreads();
  float acc[8] = {0,0,0,0,0,0,0,0};
  for (int k = 0; k < kH; ++k){
    const float bkj = A[(size_t)k*kH + j];
    #pragma unroll
    for (int r = 0; r < 8; ++r) acc[r] += ar[r][k] * bkj;
  }
  #pragma unroll
  for (int r = 0; r < 8; ++r) C[(size_t)(rg*8 + r)*kH + j] = acc[r];
}

// ---------------- MFMA GEMM: C[M,N](bf16) = A[M,K](bf16) @ W[N,K]^T + bias ----
__global__ __launch_bounds__(256) void gemm_bf16(
    const ushort* __restrict__ A, const ushort* __restrict__ W,
    ushort* __restrict__ C, int M, int N, int K,
    const float* __restrict__ pb1, const float* __restrict__ pb2, float bscale)
{
  const int wave = threadIdx.x >> 6, lane = threadIdx.x & 63;
  const int task = blockIdx.x*4 + wave;
  const int NT = N >> 6;
  const int mt = task / NT, ng = task % NT;
  const int r = lane & 15, quad = lane >> 4;

  const ushort* ap = A + (size_t)(mt*16 + r)*K + quad*8;
  const ushort* wp = W + (size_t)(ng*64 + r)*K + quad*8;
  f32x4 ac0 = {0,0,0,0}, ac1 = {0,0,0,0}, ac2 = {0,0,0,0}, ac3 = {0,0,0,0};
  for (int k0 = 0; k0 < K; k0 += 32){
    short8 av = *(const short8*)(ap + k0);
    short8 b0 = *(const short8*)(wp + k0);
    short8 b1 = *(const short8*)(wp + (size_t)16*K + k0);
    short8 b2 = *(const short8*)(wp + (size_t)32*K + k0);
    short8 b3 = *(const short8*)(wp + (size_t)48*K + k0);
    ac0 = __builtin_amdgcn_mfma_f32_16x16x32_bf16(av, b0, ac0, 0, 0, 0);
    ac1 = __builtin_amdgcn_mfma_f32_16x16x32_bf16(av, b1, ac1, 0, 0, 0);
    ac2 = __builtin_amdgcn_mfma_f32_16x16x32_bf16(av, b2, ac2, 0, 0, 0);
    ac3 = __builtin_amdgcn_mfma_f32_16x16x32_bf16(av, b3, ac3, 0, 0, 0);
  }
  const f32x4 accs[4] = {ac0, ac1, ac2, ac3};
  #pragma unroll
  for (int j = 0; j < 4; ++j){
    const int nn = ng*64 + j*16 + r;
    float bias = 0.f;
    if (pb1) bias += pb1[nn];
    if (pb2) bias += pb2[nn];
    bias *= bscale;
    #pragma unroll
    for (int i = 0; i < 4; ++i){
      const int mm = mt*16 + quad*4 + i;
      C[(size_t)mm*N + nn] = f2b(accs[j][i] + bias);
    }
  }
}

// ================= chunked scan, MFMA + double-buffered LDS =================
// grid = 128 blocks = 32 chunks x 4 batch-groups of 16 batches; 8 waves/block.
// Per step: nh[16,512] = 0.9*h + U_t + (h_hi + h_lo)@G^T   (hi/lo bf16 split)
// MFMA roles: A = G rows (output cols), B = h (batch cols).
// Double-buffered fragment tiles -> ONE barrier per step (read cur, write cur^1).
// LDS XOR-swizzled (byte ^= (row&7)<<4) for conflict-free ds_read_b128.
// FULL=false: zero-init, write chunk-end state to Z.
// FULL=true : init from S, write every step to nh (bf16).
template<bool FULL>
__global__ __launch_bounds__(512) void scan_mfma(
    const ushort* __restrict__ U,     // (B,S,H) bf16
    const ushort* __restrict__ G,     // (H,H) bf16 row-major [n][m] = bf16(0.1*Wh)
    const float* __restrict__ S,      // (B,NC,H) chunk-entry states (FULL only)
    float* __restrict__ Z,            // (B,NC,H) chunk-end states (!FULL only)
    ushort* __restrict__ nh)          // (B,S,H) bf16 (FULL only)
{
  const int c  = blockIdx.x & (kNC - 1);
  const int b0 = (blockIdx.x >> 5) * 16;
  const int wave = threadIdx.x >> 6, lane = threadIdx.x & 63;
  const int r = lane & 15, quad = lane >> 4;
  const int wbase = wave * 64;        // this wave's 64 output columns
  const int colq = quad * 4;          // column sub-offset within a 16-tile

  __shared__ __align__(16) ushort hiL[2][16*kH];
  __shared__ __align__(16) ushort loL[2][16*kH];

  // swizzled byte offset into a [16][512] bf16 tile
  #define SWZ(row, bytecol) ((row)*1024 + ((bytecol) ^ (((row)&7) << 4)))

  // G row pointers: tile t -> row wbase + t*16 + r, k-slice quad*8
  const ushort* gp0 = G + (size_t)(wbase +  0 + r)*kH + quad*8;
  const ushort* gp1 = G + (size_t)(wbase + 16 + r)*kH + quad*8;
  const ushort* gp2 = G + (size_t)(wbase + 32 + r)*kH + quad*8;
  const ushort* gp3 = G + (size_t)(wbase + 48 + r)*kH + quad*8;

  // this thread: batch = b0 + r; output cols wbase + t*16 + colq + i (i=0..3)
  float st[4][4];
  #pragma unroll
  for (int t = 0; t < 4; ++t){
    if (FULL){
      const float4 s4 = *(const float4*)&S[((size_t)(b0 + r)*kNC + c)*kH
                                           + wbase + t*16 + colq];
      st[t][0] = s4.x; st[t][1] = s4.y; st[t][2] = s4.z; st[t][3] = s4.w;
    } else {
      st[t][0] = st[t][1] = st[t][2] = st[t][3] = 0.f;
    }
  }

  // initial fragments into buffer 0 (packed hi/lo, vector LDS writes)
  #pragma unroll
  for (int t = 0; t < 4; ++t){
    ushort h[4], l[4];
    #pragma unroll
    for (int i = 0; i < 4; ++i){
      h[i] = f2b(st[t][i]);
      l[i] = f2b(st[t][i] - b2f(h[i]));
    }
    uint2 hw, lw;
    hw.x = (unsigned)h[0] | ((unsigned)h[1] << 16);
    hw.y = (unsigned)h[2] | ((unsigned)h[3] << 16);
    lw.x = (unsigned)l[0] | ((unsigned)l[1] << 16);
    lw.y = (unsigned)l[2] | ((unsigned)l[3] << 16);
    const int bc = (wbase + t*16 + colq) * 2;
    *(uint2*)((char*)hiL[0] + SWZ(r, bc)) = hw;
    *(uint2*)((char*)loL[0] + SWZ(r, bc)) = lw;
  }
  __syncthreads();

  const size_t ubase = (size_t)(b0 + r)*kS*kH;
  int cur = 0;

  for (int jj = 0; jj < kC; ++jj){
    const int tt = c*kC + jj;

    // prefetch this step's U (latency hides under the MFMA loop)
    uint2 uv[4];
    #pragma unroll
    for (int t = 0; t < 4; ++t)
      uv[t] = *(const uint2*)&U[ubase + (size_t)tt*kH + wbase + t*16 + colq];

    const char* rdHi = (const char*)hiL[cur];
    const char* rdLo = (const char*)loL[cur];
    char* wrHi = (char*)hiL[cur ^ 1];
    char* wrLo = (char*)loL[cur ^ 1];

    f32x4 ah0 = {0,0,0,0}, ah1 = {0,0,0,0}, ah2 = {0,0,0,0}, ah3 = {0,0,0,0};
    f32x4 al0 = {0,0,0,0}, al1 = {0,0,0,0}, al2 = {0,0,0,0}, al3 = {0,0,0,0};
    __builtin_amdgcn_s_setprio(1);
    #pragma unroll 2
    for (int k0 = 0; k0 < kH; k0 += 32){
      const int rb = k0*2 + quad*16;   // 16B-aligned, swizzle-safe
      const short8 bh = *(const short8*)(rdHi + SWZ(r, rb));
      const short8 bl = *(const short8*)(rdLo + SWZ(r, rb));
      const short8 g0 = *(const short8*)(gp0 + k0);
      const short8 g1 = *(const short8*)(gp1 + k0);
      const short8 g2 = *(const short8*)(gp2 + k0);
      const short8 g3 = *(const short8*)(gp3 + k0);
      ah0 = __builtin_amdgcn_mfma_f32_16x16x32_bf16(g0, bh, ah0, 0, 0, 0);
      ah1 = __builtin_amdgcn_mfma_f32_16x16x32_bf16(g1, bh, ah1, 0, 0, 0);
      ah2 = __builtin_amdgcn_mfma_f32_16x16x32_bf16(g2, bh, ah2, 0, 0, 0);
      ah3 = __builtin_amdgcn_mfma_f32_16x16x32_bf16(g3, bh, ah3, 0, 0, 0);
      al0 = __builtin_amdgcn_mfma_f32_16x16x32_bf16(g0, bl, al0, 0, 0, 0);
      al1 = __builtin_amdgcn_mfma_f32_16x16x32_bf16(g1, bl, al1, 0, 0, 0);
      al2 = __builtin_amdgcn_mfma_f32_16x16x32_bf16(g2, bl, al2, 0, 0, 0);
      al3 = __builtin_amdgcn_mfma_f32_16x16x32_bf16(g3, bl, al3, 0, 0, 0);
    }
    __builtin_amdgcn_s_setprio(0);
    const f32x4 acs[4] = {ah0 + al0, ah1 + al1, ah2 + al2, ah3 + al3};

    #pragma unroll
    for (int t = 0; t < 4; ++t){
      float u0, u1, u2, u3;
      unpack2(uv[t].x, u0, u1); unpack2(uv[t].y, u2, u3);
      const float n0 = 0.9f*st[t][0] + u0 + acs[t][0];
      const float n1 = 0.9f*st[t][1] + u1 + acs[t][1];
      const float n2 = 0.9f*st[t][2] + u2 + acs[t][2];
      const float n3 = 0.9f*st[t][3] + u3 + acs[t][3];
      st[t][0] = n0; st[t][1] = n1; st[t][2] = n2; st[t][3] = n3;
      const ushort h0 = f2b(n0), h1 = f2b(n1), h2 = f2b(n2), h3 = f2b(n3);
      const ushort l0 = f2b(n0 - b2f(h0)), l1 = f2b(n1 - b2f(h1));
      const ushort l2 = f2b(n2 - b2f(h2)), l3 = f2b(n3 - b2f(h3));
      uint2 hw, lw;
      hw.x = (unsigned)h0 | ((unsigned)h1 << 16);
      hw.y = (unsigned)h2 | ((unsigned)h3 << 16);
      lw.x = (unsigned)l0 | ((unsigned)l1 << 16);
      lw.y = (unsigned)l2 | ((unsigned)l3 << 16);
      const int bc = (wbase + t*16 + colq) * 2;
      *(uint2*)(wrHi + SWZ(r, bc)) = hw;
      *(uint2*)(wrLo + SWZ(r, bc)) = lw;
      if (FULL)
        *(uint2*)&nh[ubase + (size_t)tt*kH + wbase + t*16 + colq] = hw;
    }
    __syncthreads();   // single barrier: writes to cur^1 visible, reads of cur done
    cur ^= 1;
  }

  if (!FULL){
    #pragma unroll
    for (int t = 0; t < 4; ++t){
      float4 z4; z4.x = st[t][0]; z4.y = st[t][1]; z4.z = st[t][2]; z4.w = st[t][3];
      *(float4*)&Z[((size_t)(b0 + r)*kNC + c)*kH + wbase + t*16 + colq] = z4;
    }
  }
  #undef SWZ
}

// boundary recursion: S[b][c] = state entering chunk c; s' = s@A16 + Z[b][c]
__global__ __launch_bounds__(512) void scan_boundary(
    const float* __restrict__ A32, const float* __restrict__ Z,
    float* __restrict__ S)
{
  const int b = blockIdx.x, n = threadIdx.x;
  __shared__ float s[kH];
  s[n] = 0.f;
  __syncthreads();
  for (int c = 0; c < kNC; ++c){
    S[((size_t)b*kNC + c)*kH + n] = s[n];
    float acc = 0.f;
    for (int m = 0; m < kH; ++m) acc += s[m] * A32[(size_t)m*kH + n];
    const float nv = acc + Z[((size_t)b*kNC + c)*kH + n];
    __syncthreads();
    s[n] = nv;
    __syncthreads();
  }
}

// ---------------- LayerNorm rows (in place on bf16) ----------------
__global__ __launch_bounds__(512) void ln_rows(
    ushort* __restrict__ act, const float* __restrict__ g, const float* __restrict__ bta)
{
  const size_t row = blockIdx.x;
  const int n = threadIdx.x, wid = n >> 6, lane = n & 63;
  __shared__ float red[16];
  const float y = b2f(act[row*kH + n]);
  float s1 = y, s2 = y*y;
  #pragma unroll
  for (int off = 32; off; off >>= 1){
    s1 += __shfl_down(s1, off); s2 += __shfl_down(s2, off);
  }
  if (lane == 0){ red[wid] = s1; red[8 + wid] = s2; }
  __syncthreads();
  float m = 0.f, q = 0.f;
  #pragma unroll
  for (int i = 0; i < 8; ++i){ m += red[i]; q += red[8+i]; }
  m *= (1.f/kH); q *= (1.f/kH);
  const float var = q - m*m;
  const float hv = (y - m) * rsqrtf(var + EPS) * g[n] + bta[n];
  act[row*kH + n] = f2b(hv);
}

// ---------------- seqmean (fp32) from bf16 act ----------------
__global__ __launch_bounds__(512) void seqmean_k(
    const ushort* __restrict__ act, float* __restrict__ seqmean)
{
  const int b = blockIdx.x, n = threadIdx.x;
  float acc = 0.f;
  for (int t = 0; t < kS; ++t) acc += b2f(act[((size_t)b*kS + t)*kH + n]);
  seqmean[(size_t)b*kH + n] = acc * (1.f/kS);
}

// ---------------- flash attention on precomputed qkv (bf16) ----------------
// grid = 16 batches x 8 heads x 2 query-halves = 256 blocks.
// lane = 2*qi + dh; each lane owns one query and HALF the head dim.
__global__ __launch_bounds__(512) void attn_chunk(
    const ushort* __restrict__ qkv,   // (16*S, 3H) bf16
    float* __restrict__ aomean, int b0)
{
  const int bb = blockIdx.x >> 4;          // batch within chunk
  const int h  = (blockIdx.x >> 1) & 7;    // head
  const int qh = blockIdx.x & 1;           // query half
  const int tid = threadIdx.x, lane = tid & 63, wave = tid >> 6;
  const int dh = lane & 1;                 // dim half
  const int q  = qh*256 + wave*32 + (lane >> 1);

  __shared__ ushort kt[128][72];
  __shared__ ushort vt[128][72];
  __shared__ float aom[kDH];
  if (tid < kDH) aom[tid] = 0.f;

  float qv[32], o[32];
  {
    const uint4* qp = (const uint4*)(qkv + ((size_t)bb*kS + q)*(3*kH) + h*kDH + dh*32);
    #pragma unroll
    for (int i = 0; i < 4; ++i){
      uint4 u = qp[i]; float f0,f1,f2,f3,f4,f5,f6,f7;
      unpack2(u.x,f0,f1); unpack2(u.y,f2,f3); unpack2(u.z,f4,f5); unpack2(u.w,f6,f7);
      qv[i*8+0]=f0*0.125f; qv[i*8+1]=f1*0.125f; qv[i*8+2]=f2*0.125f; qv[i*8+3]=f3*0.125f;
      qv[i*8+4]=f4*0.125f; qv[i*8+5]=f5*0.125f; qv[i*8+6]=f6*0.125f; qv[i*8+7]=f7*0.125f;
    }
  }
  #pragma unroll
  for (int d = 0; d < 32; ++d) o[d] = 0.f;
  float mmax = -1e30f, lsum = 0.f;

  const int p  = tid & 127;
  const int dg = (tid >> 7) * 16;

  for (int t0 = 0; t0 < kS; t0 += 128){
    __syncthreads();
    const ushort* krow = qkv + ((size_t)bb*kS + t0 + p)*(3*kH) + kH   + h*kDH + dg;
    const ushort* vrow = qkv + ((size_t)bb*kS + t0 + p)*(3*kH) + 2*kH + h*kDH + dg;
    *(uint4*)&kt[p][dg]     = *(const uint4*)krow;
    *(uint4*)&kt[p][dg + 8] = *(const uint4*)(krow + 8);
    *(uint4*)&vt[p][dg]     = *(const uint4*)vrow;
    *(uint4*)&vt[p][dg + 8] = *(const uint4*)(vrow + 8);
    __syncthreads();

    for (int j = 0; j < 128; ++j){
      float sh = 0.f;
      const uint4* kp = (const uint4*)&kt[j][dh*32];
      #pragma unroll
      for (int i = 0; i < 4; ++i){
        uint4 u = kp[i]; float f0,f1,f2,f3,f4,f5,f6,f7;
        unpack2(u.x,f0,f1); unpack2(u.y,f2,f3); unpack2(u.z,f4,f5); unpack2(u.w,f6,f7);
        sh += qv[i*8+0]*f0 + qv[i*8+1]*f1 + qv[i*8+2]*f2 + qv[i*8+3]*f3
            + qv[i*8+4]*f4 + qv[i*8+5]*f5 + qv[i*8+6]*f6 + qv[i*8+7]*f7;
      }
      const float s = sh + __shfl_xor(sh, 1);   // combine the two dim-halves
      if (s > mmax){
        const float corr = __expf(mmax - s);
        lsum *= corr;
        #pragma unroll
        for (int d = 0; d < 32; ++d) o[d] *= corr;
        mmax = s;
      }
      const float pw = __expf(s - mmax);
      lsum += pw;
      const uint4* vp = (const uint4*)&vt[j][dh*32];
      #pragma unroll
      for (int i = 0; i < 4; ++i){
        uint4 u = vp[i]; float f0,f1,f2,f3,f4,f5,f6,f7;
        unpack2(u.x,f0,f1); unpack2(u.y,f2,f3); unpack2(u.z,f4,f5); unpack2(u.w,f6,f7);
        o[i*8+0] += pw*f0; o[i*8+1] += pw*f1; o[i*8+2] += pw*f2; o[i*8+3] += pw*f3;
        o[i*8+4] += pw*f4; o[i*8+5] += pw*f5; o[i*8+6] += pw*f6; o[i*8+7] += pw*f7;
      }
    }
  }
  const float invl = (1.f / lsum) * (1.f/kS);
  #pragma unroll
  for (int d = 0; d < 32; ++d){
    float v = o[d] * invl;
    #pragma unroll
    for (int off = 2; off < 64; off <<= 1) v += __shfl_xor(v, off);
    if ((lane >> 1) == 0) atomicAdd(&aom[dh*32 + d], v);  // lanes 0 and 1
  }
  __syncthreads();
  if (tid < kDH)
    atomicAdd(&aomean[(size_t)(b0 + bb)*kH + h*kDH + tid], aom[tid]);
}

// ---- pooled = seqmean + aomean@out_w^T + out_b (fp32) ----
__global__ __launch_bounds__(512) void pooled_kernel(
    const float* __restrict__ seqmean, const float* __restrict__ aomean,
    const float* __restrict__ outw, const float* __restrict__ outb,
    float* __restrict__ pooled)
{
  const int b = blockIdx.x, n = threadIdx.x;
  __shared__ float a[kH];
  a[n] = aomean[(size_t)b*kH + n];
  __syncthreads();
  const float* w = outw + (size_t)n*kH;
  float acc = outb[n];
  for (int m = 0; m < kH; ++m) acc += w[m] * a[m];
  pooled[(size_t)b*kH + n] = seqmean[(size_t)b*kH + n] + acc;
}

// ---------------- heads (fp32, validated) ----------------
__global__ __launch_bounds__(256) void heads_kernel(
    const float* __restrict__ pooled,
    const float* Wd1, const float* bd1, const float* Wd2, const float* bd2,
    const float* Wd3, const float* bd3,
    const float* Wq1, const float* bq1, const float* Wq2, const float* bq2,
    const float* Wq3, const float* bq3,
    const float* Wc1, const float* bc1, const float* Wc2, const float* bc2,
    float* __restrict__ out)
{
  const int b = blockIdx.x, tid = threadIdx.x;
  __shared__ float p[kH];
  __shared__ float a1d[256], a1q[256], a1c[256];
  __shared__ float a2d[128], a2q[128];
  p[tid]       = pooled[(size_t)b*kH + tid];
  p[tid + 256] = pooled[(size_t)b*kH + tid + 256];
  __syncthreads();
  {
    const float *w1 = Wd1 + (size_t)tid*kH, *w2 = Wq1 + (size_t)tid*kH,
                *w3 = Wc1 + (size_t)tid*kH;
    float v1 = bd1[tid], v2 = bq1[tid], v3 = bc1[tid];
    for (int m = 0; m < kH; ++m){
      v1 += w1[m]*p[m]; v2 += w2[m]*p[m]; v3 += w3[m]*p[m];
    }
    a1d[tid] = fmaxf(v1, 0.f); a1q[tid] = fmaxf(v2, 0.f); a1c[tid] = fmaxf(v3, 0.f);
  }
  __syncthreads();
  if (tid < 128){
    const float *w1 = Wd2 + (size_t)tid*256, *w2 = Wq2 + (size_t)tid*256;
    float v1 = bd2[tid], v2 = bq2[tid];
    for (int m = 0; m < 256; ++m){ v1 += w1[m]*a1d[m]; v2 += w2[m]*a1q[m]; }
    a2d[tid] = fmaxf(v1, 0.f); a2q[tid] = fmaxf(v2, 0.f);
  }
  __syncthreads();
  if (tid == 0){
    float d0 = bd3[0], d1 = bd3[1], pr = bq3[0], c = bc2[0];
    for (int m = 0; m < 128; ++m){
      d0 += Wd3[m]*a2d[m]; d1 += Wd3[128+m]*a2d[m]; pr += Wq3[m]*a2q[m];
    }
    for (int m = 0; m < 256; ++m) c += Wc2[m]*a1c[m];
    c = 1.f / (1.f + __expf(-c));
    out[2*b + 0]  = d0;
    out[2*b + 1]  = d1;
    out[2*kB + b] = pr;
    out[3*kB + b] = c;
  }
}

// ---------------- launch ----------------
extern "C" void kernel_launch(void* const* d_in, const int* in_sizes, int n_in,
                              void* d_out, int out_size, void* d_ws, size_t ws_size,
                              hipStream_t stream) {
  const float* x    = (const float*)d_in[0];
  const float* Win0 = (const float*)d_in[1];
  const float* bin0 = (const float*)d_in[2];
  const float* Wi   = (const float*)d_in[3];
  const float* bi   = (const float*)d_in[4];
  const float* Wh   = (const float*)d_in[5];
  const float* bh   = (const float*)d_in[6];
  const float* Wo   = (const float*)d_in[7];
  const float* bo   = (const float*)d_in[8];
  const float* lng  = (const float*)d_in[9];
  const float* lnb  = (const float*)d_in[10];
  const float* ipw  = (const float*)d_in[11];
  const float* ipb  = (const float*)d_in[12];
  const float* outw = (const float*)d_in[13];
  const float* outb = (const float*)d_in[14];

  char* wsb = (char*)d_ws;
  const size_t MB = 1u << 20;
  ushort* act   = (ushort*)(wsb);               // 32 MiB
  ushort* U     = (ushort*)(wsb + 32*MB);       // 32 MiB (reused as qkv)
  ushort* nh    = (ushort*)(wsb + 64*MB);       // 32 MiB
  ushort* wh_bf = (ushort*)(wsb + 96*MB);       // 2 MiB (0.1-scaled Wh, row-major [n][m])
  ushort* wi_bf = (ushort*)(wsb + 98*MB);       // 2 MiB (0.1-scaled)
  ushort* wo_bf = (ushort*)(wsb + 100*MB);      // 2 MiB
  float*  Afp   = (float*)(wsb + 102*MB);       // 4 MiB (fp32 A powers, ping; ends A^16)
  float*  Afp2  = (float*)(wsb + 106*MB);       // 4 MiB (pong; reused as Z after sqgemms)
  float*  Z     = Afp2;                         // 4 MiB (B*NC*H fp32, NC=32)
  float*  S     = (float*)(wsb + 110*MB);       // 4 MiB (chunk-entry true states)
  ushort* w0_bf = (ushort*)(wsb + 114*MB);      // 64 KiB
  ushort* ip_bf = (ushort*)(wsb + 114*MB + 65536);            // 1.5 MiB
  ushort* x_bf  = (ushort*)(wsb + 114*MB + 65536 + 1572864);  // 4 MiB
  char*   tail  = wsb + 114*MB + 65536 + 1572864 + 4194304;
  float* seqmean = (float*)tail;
  float* aomean  = seqmean + (size_t)kB*kH;
  float* pooled  = aomean  + (size_t)kB*kH;
  ushort* qkv    = U;   // overlay: U dead after scan phase

  // ---- prep casts ----
  cast_scale<<<(kB*kS*kF + 255)/256, 256, 0, stream>>>(x, x_bf, kB*kS*kF, 1.f);
  cast_scale<<<(kH*kF + 255)/256, 256, 0, stream>>>(Win0, w0_bf, kH*kF, 1.f);
  cast_scale<<<(kL*kH*kH + 255)/256, 256, 0, stream>>>(Wi, wi_bf, kL*kH*kH, 0.1f);
  cast_scale<<<(kL*kH*kH + 255)/256, 256, 0, stream>>>(Wo, wo_bf, kL*kH*kH, 1.f);
  cast_scale<<<(kL*kH*kH + 255)/256, 256, 0, stream>>>(Wh, wh_bf, kL*kH*kH, 0.1f);
  cast_scale<<<(3*kH*kH + 255)/256, 256, 0, stream>>>(ipw, ip_bf, 3*kH*kH, 1.f);
  prep_afp<<<(kL*kH*kH + 255)/256, 256, 0, stream>>>(Wh, Afp);
  // A^16 for all 4 layers via 4 fp32 squarings (ends in Afp)
  sqgemm<<<kL*64, 512, 0, stream>>>(Afp,  Afp2);   // A^2
  sqgemm<<<kL*64, 512, 0, stream>>>(Afp2, Afp);    // A^4
  sqgemm<<<kL*64, 512, 0, stream>>>(Afp,  Afp2);   // A^8
  sqgemm<<<kL*64, 512, 0, stream>>>(Afp2, Afp);    // A^16

  constexpr int M = kB*kS;   // 32768
  gemm_bf16<<<(M/16)*(kH/64)/4, 256, 0, stream>>>(x_bf, w0_bf, act, M, kH, kF,
                                                  bin0, nullptr, 1.f);
  for (int l = 0; l < kL; ++l){
    gemm_bf16<<<(M/16)*(kH/64)/4, 256, 0, stream>>>(
        act, wi_bf + (size_t)l*kH*kH, U, M, kH, kH,
        bi + (size_t)l*kH, bh + (size_t)l*kH, 0.1f);
    scan_mfma<false><<<128, 512, 0, stream>>>(U, wh_bf + (size_t)l*kH*kH,
                                              nullptr, Z, nullptr);
    scan_boundary<<<kB, kH, 0, stream>>>(Afp + (size_t)l*kH*kH, Z, S);
    scan_mfma<true><<<128, 512, 0, stream>>>(U, wh_bf + (size_t)l*kH*kH,
                                             S, nullptr, nh);
    gemm_bf16<<<(M/16)*(kH/64)/4, 256, 0, stream>>>(
        nh, wo_bf + (size_t)l*kH*kH, act, M, kH, kH,
        bo + (size_t)l*kH, nullptr, 1.f);
    ln_rows<<<M, kH, 0, stream>>>(act, lng + (size_t)l*kH, lnb + (size_t)l*kH);
  }

  seqmean_k<<<kB, kH, 0, stream>>>(act, seqmean);

  zero_f32<<<(kB*kH + 255)/256, 256, 0, stream>>>(aomean, kB*kH);
  for (int c = 0; c < 4; ++c){
    const int Mc = 16*kS;   // 8192
    gemm_bf16<<<(Mc/16)*(3*kH/64)/4, 256, 0, stream>>>(
        act + (size_t)c*Mc*kH, ip_bf, qkv, Mc, 3*kH, kH, ipb, nullptr, 1.f);
    attn_chunk<<<16*8*2, 512, 0, stream>>>(qkv, aomean, c*16);
  }

  pooled_kernel<<<kB, kH, 0, stream>>>(seqmean, aomean, outw, outb, pooled);

  heads_kernel<<<kB, 256, 0, stream>>>(pooled,
      (const float*)d_in[15], (const float*)d_in[16], (const float*)d_in[17],
      (const float*)d_in[18], (const float*)d_in[19], (const float*)d_in[20],
      (const float*)d_in[21], (const float*)d_in[22], (const float*)d_in[23],
      (const float*)d_in[24], (const float*)d_in[25], (const float*)d_in[26],
      (const float*)d_in[27], (const float*)d_in[28], (const float*)d_in[29],
      (const float*)d_in[30], (float*)d_out);
}